// Round 11
// baseline (1718.504 us; speedup 1.0000x reference)
//
#include <hip/hip_runtime.h>
#include <hip/hip_bf16.h>
#include <hip/hip_cooperative_groups.h>

namespace cg = cooperative_groups;

#define N_NODES 30000
#define N_EDGES 480000
#define NFEAT 92
#define EFEAT 50
#define D1 64
#define ZD 178
#define NL 3
#define NG 256
#define BN_EPS 1e-5f
#define NTILES (N_EDGES / 16)  // 30000
#define SCAN_BLOCKS ((N_NODES + 255) / 256)  // 118

typedef __attribute__((ext_vector_type(8))) short bf16x8;
typedef __attribute__((ext_vector_type(8))) unsigned short u16x8;
typedef __attribute__((ext_vector_type(4))) unsigned short u16x4;
typedef __attribute__((ext_vector_type(4))) float f32x4;

static __device__ __forceinline__ unsigned short f2bf(float v) {
  __hip_bfloat16 b = __float2bfloat16(v);
  return *(unsigned short*)&b;
}
static __device__ __forceinline__ float bfu(unsigned short u) {
  union { unsigned int i; float f; } c;
  c.i = ((unsigned int)u) << 16;
  return c.f;
}

struct MegaArgs {
  const float *x, *ea;
  const float *lin0_w, *lin0_b, *conv_wf, *conv_bf, *conv_ws, *conv_bs;
  const float *bn_gamma, *bn_beta, *lin1_w, *lin1_b, *fc_w, *fc_b, *lin2_w, *lin2_b;
  const int *ei, *batch;
  float *h0, *h1;
  unsigned short *projd_pk, *projs_pk;
  float *aggrA, *aggrB, *musum, *sqsum, *invc;
  int *cnt, *lpre, *ptot, *wptr, *srcs, *dsts, *grp;
  unsigned short *eapb, *Bp;
  float* out;
};

// One persistent cooperative kernel; phases separated by grid.sync().
// LDS is a union (max phase = edgemm's 17408 B), not a sum.
extern "C" __global__ void __launch_bounds__(256)
k_mega(MegaArgs a) {
  cg::grid_group grid = cg::this_grid();
  __shared__ __align__(16) char smem[17408];
  const int tid = threadIdx.x;
  const int nb = gridDim.x;
  const int gthreads = nb * 256;
  const int gwaves = nb * 4;
  const int lane = tid & 63;
  const int wv = tid >> 6;
  const int gwid = blockIdx.x * 4 + wv;
  const int col = lane & 15;
  const int quad = lane >> 4;

  // ============ phase 0: zero cnt, lin0 (+zero aggrA), wprep ============
  for (int i = blockIdx.x * 256 + tid; i < N_NODES; i += gthreads) a.cnt[i] = 0;
  {
    float wreg[NFEAT];
#pragma unroll
    for (int k = 0; k < NFEAT; ++k) wreg[k] = a.lin0_w[k * D1 + lane];
    const float bj = a.lin0_b[lane];
    for (int i = gwid; i < N_NODES; i += gwaves) {
      const float2* xr = (const float2*)(a.x + (size_t)i * NFEAT);
      float acc = bj;
#pragma unroll
      for (int k = 0; k < NFEAT / 2; ++k) {
        const float2 v = xr[k];
        acc = fmaf(v.x, wreg[2 * k], acc);
        acc = fmaf(v.y, wreg[2 * k + 1], acc);
      }
      a.h0[(size_t)i * D1 + lane] = fmaxf(acc, 0.0f);
      a.aggrA[(size_t)i * D1 + lane] = 0.0f;
    }
  }
  for (int idx = blockIdx.x * 256 + tid; idx < NL * 16 * 64 * 8; idx += gthreads) {
    const int j = idx & 7;
    const int ln = (idx >> 3) & 63;
    const int frag = (idx >> 9) & 15;  // (m*2+t)*4+n
    const int l = idx >> 13;
    const int n = frag & 3;
    const int t = (frag >> 2) & 1;
    const int m = frag >> 3;
    const int k = t * 32 + (ln >> 4) * 8 + j;
    const int feat = (ln & 15) * 4 + n;
    float v = 0.0f;
    if (k < EFEAT) {
      const float* W = (m == 0) ? a.conv_wf : a.conv_ws;
      v = W[(size_t)l * ZD * D1 + (size_t)(128 + k) * D1 + feat];
    }
    a.Bp[idx] = f2bf(v);
  }
  __threadfence();
  grid.sync();

  // ============ phase 1: dst counts ============
  for (int e = blockIdx.x * 256 + tid; e < N_EDGES; e += gthreads)
    atomicAdd(&a.cnt[a.ei[N_EDGES + e]], 1);
  __threadfence();
  grid.sync();

  // ============ phase 2: scan1 (per-logical-block prefix) ============
  {
    int* bs = (int*)smem;
    for (int lb = blockIdx.x; lb < SCAN_BLOCKS; lb += nb) {
      const int idx = lb * 256 + tid;
      const int v = (idx < N_NODES) ? a.cnt[idx] : 0;
      bs[tid] = v;
      __syncthreads();
      for (int off = 1; off < 256; off <<= 1) {
        int u = (tid >= off) ? bs[tid - off] : 0;
        __syncthreads();
        bs[tid] += u;
        __syncthreads();
      }
      if (idx < N_NODES) a.lpre[idx] = bs[tid] - v;
      if (tid == 255) a.ptot[lb] = bs[255];
      __syncthreads();
    }
  }
  __threadfence();
  grid.sync();

  // ============ phase 3: scan23 (redundant top scan + wptr/invc/grp) ============
  {
    int* bs = (int*)smem;
    if (tid < 128) bs[tid] = (tid < SCAN_BLOCKS) ? a.ptot[tid] : 0;
    __syncthreads();
    for (int off = 1; off < 128; off <<= 1) {
      int u = 0;
      if (tid < 128 && tid >= off) u = bs[tid - off];
      __syncthreads();
      if (tid < 128 && tid >= off) bs[tid] += u;
      __syncthreads();
    }
    for (int idx = blockIdx.x * 256 + tid; idx < N_NODES; idx += gthreads) {
      const int bid = idx >> 8;
      const int boff = (bid == 0) ? 0 : bs[bid - 1];
      a.wptr[idx] = boff + a.lpre[idx];
      a.invc[idx] = 1.0f / fmaxf((float)a.cnt[idx], 1.0f);
      const int bt = a.batch[idx];
      if (idx == 0)
        for (int g = 0; g <= bt; ++g) a.grp[g] = 0;
      else {
        const int pb = a.batch[idx - 1];
        for (int g = pb + 1; g <= bt; ++g) a.grp[g] = idx;
      }
      if (idx == N_NODES - 1)
        for (int g = bt + 1; g <= NG; ++g) a.grp[g] = N_NODES;
    }
  }
  __threadfence();
  grid.sync();

  // ============ phase 4: build (CSR scatter + bf16 pack in CSR order) ============
  {
    int* lpos = (int*)smem;
    for (int lb = blockIdx.x; lb < N_EDGES / 256; lb += nb) {
      const int e0 = lb * 256;
      {
        const int e = e0 + tid;
        const int d = a.ei[N_EDGES + e];
        const int pos = atomicAdd(&a.wptr[d], 1);
        a.srcs[pos] = a.ei[e];
        a.dsts[pos] = d;
        lpos[tid] = pos;
      }
      __syncthreads();
      const int l16 = tid & 15;
      const int sub = tid >> 4;
#pragma unroll
      for (int r = 0; r < 16; ++r) {
        const int eb = r * 16 + sub;
        const size_t ge = e0 + eb;
        const int pos = lpos[eb];
        unsigned short o0 = 0, o1 = 0, o2 = 0, o3 = 0;
        if (l16 < 12) {
          const float4 v = *(const float4*)(a.ea + ge * EFEAT + l16 * 4);
          o0 = f2bf(v.x); o1 = f2bf(v.y); o2 = f2bf(v.z); o3 = f2bf(v.w);
        } else if (l16 == 12) {
          const float2 v = *(const float2*)(a.ea + ge * EFEAT + 48);
          o0 = f2bf(v.x); o1 = f2bf(v.y);
        }
        u16x4 st;
        st[0] = o0; st[1] = o1; st[2] = o2; st[3] = o3;
        *(u16x4*)(a.eapb + ((size_t)pos << 6) + l16 * 4) = st;
      }
      __syncthreads();
    }
  }
  __threadfence();
  grid.sync();

  // ============ layers ============
  for (int l = 0; l < NL; ++l) {
    const float* wfl = a.conv_wf + (size_t)l * ZD * D1;
    const float* wsl = a.conv_ws + (size_t)l * ZD * D1;
    const float* aggr_prev = (l == 1) ? a.aggrA : a.aggrB;  // unused for l==0
    float* aggr_cur = (l == 1) ? a.aggrB : a.aggrA;
    float* zb = (l == 0) ? a.aggrB : ((l == 1) ? a.aggrA : nullptr);
    const float* hin = (l < 2) ? a.h0 : a.h1;
    float* hout = (l == 1) ? a.h1 : a.h0;

    // ---- nodeproj (+ fused BN-residual-ReLU update of previous layer) ----
    {
      float(*hl)[64] = (float(*)[64])smem;
      const float* W = (wv < 2) ? wfl : wsl;
      const int roff = (wv & 1) * 64;
      float wreg[D1];
#pragma unroll
      for (int k = 0; k < D1; ++k) wreg[k] = W[(size_t)(roff + k) * D1 + lane];
      unsigned short* pk = (wv & 1) ? a.projs_pk : a.projd_pk;
      const int slot = (wv < 2) ? 0 : 4;
      const int poff = (lane >> 2) * 8 + (lane & 3) + slot;
      float r = 0.0f, sh = 0.0f;
      if (l > 0) {
        const float mu = a.musum[lane] * (1.0f / N_NODES);
        const float var = a.sqsum[lane] * (1.0f / N_NODES) - mu * mu;
        r = a.bn_gamma[(size_t)(l - 1) * D1 + lane] * rsqrtf(var + BN_EPS);
        sh = a.bn_beta[(size_t)(l - 1) * D1 + lane] - mu * r;
      }
      for (int i = blockIdx.x; i < N_NODES; i += nb) {
        float hv = hin[(size_t)i * D1 + lane];
        if (l > 0) {
          const float av = aggr_prev[(size_t)i * D1 + lane] * a.invc[i];
          hv = fmaxf(hv + fmaf(av, r, sh), 0.0f);
          if (wv == 0) hout[(size_t)i * D1 + lane] = hv;
        }
        hl[wv][lane] = hv;
        __builtin_amdgcn_wave_barrier();
        const float4* hr = (const float4*)&hl[wv][0];
        float acc = 0.0f;
#pragma unroll
        for (int k4 = 0; k4 < D1 / 4; ++k4) {
          const float4 v = hr[k4];
          acc = fmaf(v.x, wreg[4 * k4 + 0], acc);
          acc = fmaf(v.y, wreg[4 * k4 + 1], acc);
          acc = fmaf(v.z, wreg[4 * k4 + 2], acc);
          acc = fmaf(v.w, wreg[4 * k4 + 3], acc);
        }
        pk[(size_t)i * 128 + poff] = f2bf(acc);
        __builtin_amdgcn_wave_barrier();
      }
    }
    __threadfence();
    grid.sync();

    // ---- edgemm: persistent grid-stride over tiles ----
    {
      float(*mlds)[16][68] = (float(*)[16][68])smem;
      if (blockIdx.x == 0 && wv == 0) {  // zero stats accumulators for stats phase
        a.musum[lane] = 0.0f;
        a.sqsum[lane] = 0.0f;
      }
      const unsigned short* Bpl = a.Bp + (size_t)l * 16 * 64 * 8;
      const float* bfp = a.conv_bf + (size_t)l * D1;
      const float* bsp = a.conv_bs + (size_t)l * D1;
      bf16x8 Bf[2][2][4];
#pragma unroll
      for (int m = 0; m < 2; ++m)
#pragma unroll
        for (int tt = 0; tt < 2; ++tt)
#pragma unroll
          for (int n = 0; n < 4; ++n)
            Bf[m][tt][n] = *(const bf16x8*)(Bpl + ((((m * 2 + tt) * 4 + n) * 64 + lane) * 8));
      const f32x4 bf4 = *(const f32x4*)(bfp + col * 4);
      const f32x4 bs4 = *(const f32x4*)(bsp + col * 4);

      for (int t = gwid; t < NTILES; t += gwaves) {
        const int base = t * 16;
        const int4 d4 = *(const int4*)(a.dsts + base + quad * 4);
        const int4 s4 = *(const int4*)(a.srcs + base + quad * 4);
        const int* dr = (const int*)&d4;
        const int* sr = (const int*)&s4;
        const bf16x8 Af0 = *(const bf16x8*)(a.eapb + ((size_t)(base + col) << 6) + quad * 8);
        const bf16x8 Af1 = *(const bf16x8*)(a.eapb + ((size_t)(base + col) << 6) + 32 + quad * 8);

        f32x4 aF[4], aS[4];
#pragma unroll
        for (int r = 0; r < 4; ++r) {
          const int d = dr[r];
          const int s = sr[r];
          const u16x8 pd = *(const u16x8*)(a.projd_pk + (size_t)d * 128 + col * 8);
          const u16x8 ss = *(const u16x8*)(a.projs_pk + (size_t)s * 128 + col * 8);
#pragma unroll
          for (int n = 0; n < 4; ++n) {
            aF[n][r] = bfu(pd[n]) + bfu(ss[n]) + bf4[n];
            aS[n][r] = bfu(pd[n + 4]) + bfu(ss[n + 4]) + bs4[n];
          }
        }

#pragma unroll
        for (int n = 0; n < 4; ++n) {
          aF[n] = __builtin_amdgcn_mfma_f32_16x16x32_bf16(Af0, Bf[0][0][n], aF[n], 0, 0, 0);
          aF[n] = __builtin_amdgcn_mfma_f32_16x16x32_bf16(Af1, Bf[0][1][n], aF[n], 0, 0, 0);
          aS[n] = __builtin_amdgcn_mfma_f32_16x16x32_bf16(Af0, Bf[1][0][n], aS[n], 0, 0, 0);
          aS[n] = __builtin_amdgcn_mfma_f32_16x16x32_bf16(Af1, Bf[1][1][n], aS[n], 0, 0, 0);
        }

#pragma unroll
        for (int r = 0; r < 4; ++r) {
          f32x4 mv;
#pragma unroll
          for (int n = 0; n < 4; ++n) {
            const float af = aF[n][r];
            const float as = aS[n][r];
            const float sg = __builtin_amdgcn_rcpf(1.0f + __expf(-af));
            const float sp = fmaxf(as, 0.0f) + __logf(1.0f + __expf(-fabsf(as)));
            mv[n] = sg * sp;
          }
          *(f32x4*)&mlds[wv][quad * 4 + r][col * 4] = mv;
        }
        __builtin_amdgcn_wave_barrier();

        float sum = 0.0f;
        int dcur = a.dsts[base];
#pragma unroll
        for (int p = 0; p < 16; ++p) {
          sum += mlds[wv][p][lane];
          const int dnxt = (p < 15) ? a.dsts[base + p + 1] : -1;
          if (dnxt != dcur) {
            atomicAdd(&aggr_cur[(size_t)dcur * D1 + lane], sum);
            sum = 0.0f;
            dcur = dnxt;
          }
        }
        __builtin_amdgcn_wave_barrier();
      }
    }
    __threadfence();
    grid.sync();

    // ---- stats over aggr*invc (+ zero the other aggr buffer) ----
    {
      float* ls = (float*)smem;
      float* lq = ls + 256;
      float s = 0.0f, sq = 0.0f;
      for (int i = gwid; i < N_NODES; i += gwaves) {
        const float v = aggr_cur[(size_t)i * D1 + lane] * a.invc[i];
        s += v;
        sq = fmaf(v, v, sq);
        if (zb) zb[(size_t)i * D1 + lane] = 0.0f;
      }
      ls[tid] = s;
      lq[tid] = sq;
      __syncthreads();
      if (tid < 64) {
        s = ls[lane] + ls[64 + lane] + ls[128 + lane] + ls[192 + lane];
        sq = lq[lane] + lq[64 + lane] + lq[128 + lane] + lq[192 + lane];
        atomicAdd(&a.musum[lane], s);
        atomicAdd(&a.sqsum[lane], sq);
      }
      __syncthreads();
    }
    __threadfence();
    grid.sync();
  }

  // ============ poolmlp (final BN update folded in) ============
  {
    float(*red)[64] = (float(*)[64])smem;  // 4*64 floats
    float* vin = (float*)smem + 256;       // 64 floats
    const float mu = a.musum[lane] * (1.0f / N_NODES);
    const float var = a.sqsum[lane] * (1.0f / N_NODES) - mu * mu;
    const float r = a.bn_gamma[2 * D1 + lane] * rsqrtf(var + BN_EPS);
    const float sh = a.bn_beta[2 * D1 + lane] - mu * r;
    for (int g = blockIdx.x; g < NG; g += nb) {
      const int s = a.grp[g], e = a.grp[g + 1];
      float acc = 0.0f;
      for (int i = s + wv; i < e; i += 4) {
        const float hv = a.h0[(size_t)i * D1 + lane];
        const float av = a.aggrA[(size_t)i * D1 + lane] * a.invc[i];
        acc += fmaxf(hv + fmaf(av, r, sh), 0.0f);
      }
      red[wv][lane] = acc;
      __syncthreads();
      const int j = tid;
      float v = 0.0f;
      if (j < 64) {
        const float inv = 1.0f / fmaxf((float)(e - s), 1.0f);
        v = (red[0][j] + red[1][j] + red[2][j] + red[3][j]) * inv;
      }
      for (int layer = 0; layer < 3; ++layer) {
        if (j < 64) vin[j] = v;
        __syncthreads();
        if (j < 64) {
          const float* W;
          const float* B;
          if (layer == 0) {
            W = a.lin1_w;
            B = a.lin1_b;
          } else {
            W = a.fc_w + (size_t)(layer - 1) * D1 * D1;
            B = a.fc_b + (size_t)(layer - 1) * D1;
          }
          float a2 = B[j];
#pragma unroll 16
          for (int k = 0; k < D1; ++k) a2 = fmaf(vin[k], W[k * D1 + j], a2);
          v = fmaxf(a2, 0.0f);
        }
        __syncthreads();
      }
      if (j < 64) {
        float p = v * a.lin2_w[j];
#pragma unroll
        for (int off = 32; off > 0; off >>= 1) p += __shfl_down(p, off);
        if (j == 0) a.out[g] = p + a.lin2_b[0];
      }
      __syncthreads();
    }
  }
}

extern "C" void kernel_launch(void* const* d_in, const int* in_sizes, int n_in,
                              void* d_out, int out_size, void* d_ws, size_t ws_size,
                              hipStream_t stream) {
  uintptr_t p = (uintptr_t)d_ws;
  auto alloc = [&](size_t bytes) {
    p = (p + 255) & ~(size_t)255;
    void* r = (void*)p;
    p += bytes;
    return r;
  };
  MegaArgs a;
  a.x        = (const float*)d_in[0];
  a.ea       = (const float*)d_in[1];
  a.lin0_w   = (const float*)d_in[2];
  a.lin0_b   = (const float*)d_in[3];
  a.conv_wf  = (const float*)d_in[4];
  a.conv_bf  = (const float*)d_in[5];
  a.conv_ws  = (const float*)d_in[6];
  a.conv_bs  = (const float*)d_in[7];
  a.bn_gamma = (const float*)d_in[8];
  a.bn_beta  = (const float*)d_in[9];
  a.lin1_w   = (const float*)d_in[10];
  a.lin1_b   = (const float*)d_in[11];
  a.fc_w     = (const float*)d_in[12];
  a.fc_b     = (const float*)d_in[13];
  a.lin2_w   = (const float*)d_in[14];
  a.lin2_b   = (const float*)d_in[15];
  a.ei       = (const int*)d_in[16];
  a.batch    = (const int*)d_in[17];

  a.h0       = (float*)alloc((size_t)N_NODES * 64 * 4);
  a.h1       = (float*)alloc((size_t)N_NODES * 64 * 4);
  a.projd_pk = (unsigned short*)alloc((size_t)N_NODES * 128 * 2);
  a.projs_pk = (unsigned short*)alloc((size_t)N_NODES * 128 * 2);
  a.aggrA    = (float*)alloc((size_t)N_NODES * 64 * 4);
  a.aggrB    = (float*)alloc((size_t)N_NODES * 64 * 4);
  a.musum    = (float*)alloc(128 * 4);
  a.sqsum    = a.musum + 64;
  a.invc     = (float*)alloc((size_t)N_NODES * 4);
  a.cnt      = (int*)alloc((size_t)N_NODES * 4);
  a.lpre     = (int*)alloc((size_t)N_NODES * 4);
  a.ptot     = (int*)alloc((size_t)SCAN_BLOCKS * 4);
  a.wptr     = (int*)alloc((size_t)N_NODES * 4);
  a.srcs     = (int*)alloc((size_t)N_EDGES * 4);
  a.dsts     = (int*)alloc((size_t)N_EDGES * 4);
  a.grp      = (int*)alloc((size_t)(NG + 1) * 4);
  a.eapb     = (unsigned short*)alloc((size_t)N_EDGES * 64 * 2);
  a.Bp       = (unsigned short*)alloc((size_t)NL * 16 * 64 * 8 * 2);
  a.out      = (float*)d_out;

  int per = 0;
  hipOccupancyMaxActiveBlocksPerMultiprocessor(&per, (const void*)k_mega, 256, 0);
  if (per < 1) per = 1;
  int nblk = per * 256;
  if (nblk > 2048) nblk = 2048;

  void* params[] = {(void*)&a};
  hipLaunchCooperativeKernel((const void*)k_mega, dim3(nblk), dim3(256), params, 0,
                             stream);
}

// Round 12
// 624.074 us; speedup vs baseline: 2.7537x; 2.7537x over previous
//
#include <hip/hip_runtime.h>
#include <hip/hip_bf16.h>

#define N_NODES 30000
#define N_EDGES 480000
#define NFEAT 92
#define EFEAT 50
#define D1 64
#define ZD 178
#define NL 3
#define NG 256
#define BN_EPS 1e-5f
#define NTILES (N_EDGES / 16)     // 30000 tiles, 1 per wave
#define EDGE_BLOCKS 7500          // logical blocks (4 waves each)
#define EDGE_GRID 7504            // 8 XCDs x 938, guard vbid < 7500

#define LIN0_BLOCKS 512
#define CNT_BLOCKS 1875    // E / 256
#define WPREP_BLOCKS 96    // NL*16*64*8 / 256
#define SCAN_BLOCKS ((N_NODES + 255) / 256)  // 118

typedef __attribute__((ext_vector_type(8))) short bf16x8;
typedef __attribute__((ext_vector_type(8))) unsigned short u16x8;
typedef __attribute__((ext_vector_type(4))) unsigned short u16x4;
typedef __attribute__((ext_vector_type(4))) float f32x4;

static __device__ __forceinline__ unsigned short f2bf(float v) {
  __hip_bfloat16 b = __float2bfloat16(v);
  return *(unsigned short*)&b;
}
static __device__ __forceinline__ float bfu(unsigned short u) {
  union { unsigned int i; float f; } c;
  c.i = ((unsigned int)u) << 16;
  return c.f;
}

// ---------------- init: lin0 + dst counts + B fragments (block-range split) --
extern "C" __global__ void __launch_bounds__(256)
k_init(const float* __restrict__ x, const float* __restrict__ w,
       const float* __restrict__ b, float* __restrict__ h,
       const int* __restrict__ ei, int* __restrict__ cnt,
       const float* __restrict__ conv_wf, const float* __restrict__ conv_ws,
       unsigned short* __restrict__ Bp) {
  const int blk = blockIdx.x;
  if (blk < LIN0_BLOCKS) {
    const int lane = threadIdx.x & 63;
    const int wave = (blk * 256 + threadIdx.x) >> 6;
    const int nw = (LIN0_BLOCKS * 256) >> 6;
    float wreg[NFEAT];
#pragma unroll
    for (int k = 0; k < NFEAT; ++k) wreg[k] = w[k * D1 + lane];
    const float bj = b[lane];
    for (int i = wave; i < N_NODES; i += nw) {
      const float2* xr = (const float2*)(x + (size_t)i * NFEAT);
      float acc = bj;
#pragma unroll
      for (int k = 0; k < NFEAT / 2; ++k) {
        const float2 v = xr[k];
        acc = fmaf(v.x, wreg[2 * k], acc);
        acc = fmaf(v.y, wreg[2 * k + 1], acc);
      }
      h[(size_t)i * D1 + lane] = fmaxf(acc, 0.0f);
    }
  } else if (blk < LIN0_BLOCKS + CNT_BLOCKS) {
    const int e = (blk - LIN0_BLOCKS) * 256 + threadIdx.x;
    if (e < N_EDGES) atomicAdd(&cnt[ei[N_EDGES + e]], 1);
  } else {
    const int idx = (blk - LIN0_BLOCKS - CNT_BLOCKS) * 256 + threadIdx.x;
    const int j = idx & 7;
    const int lane = (idx >> 3) & 63;
    const int frag = (idx >> 9) & 15;  // (m*2+t)*4+n
    const int l = idx >> 13;
    const int n = frag & 3;
    const int t = (frag >> 2) & 1;
    const int m = frag >> 3;
    const int k = t * 32 + (lane >> 4) * 8 + j;
    const int feat = (lane & 15) * 4 + n;
    float v = 0.0f;
    if (k < EFEAT) {
      const float* W = (m == 0) ? conv_wf : conv_ws;
      v = W[(size_t)l * ZD * D1 + (size_t)(128 + k) * D1 + feat];
    }
    Bp[idx] = f2bf(v);
  }
}

// ---------------- scan phase 1: per-block partial sums ----------------
extern "C" __global__ void __launch_bounds__(256)
k_scan1(const int* __restrict__ cnt, int* __restrict__ lpre, int* __restrict__ ptot) {
  const int t = threadIdx.x;
  const int idx = blockIdx.x * 256 + t;
  const int v = (idx < N_NODES) ? cnt[idx] : 0;
  __shared__ int bs[256];
  bs[t] = v;
  __syncthreads();
  for (int off = 1; off < 256; off <<= 1) {
    int u = (t >= off) ? bs[t - off] : 0;
    __syncthreads();
    bs[t] += u;
    __syncthreads();
  }
  if (idx < N_NODES) lpre[idx] = bs[t] - v;
  if (t == 255) ptot[blockIdx.x] = bs[255];
}

// scan phase 2+3: redundant block-offset scan + wptr/invc/grp
extern "C" __global__ void __launch_bounds__(256)
k_scan23(const int* __restrict__ cnt, const int* __restrict__ lpre,
         const int* __restrict__ ptot, const int* __restrict__ batch,
         int* __restrict__ wptr, float* __restrict__ invc,
         int* __restrict__ grp) {
  __shared__ int bs[128];
  const int t = threadIdx.x;
  if (t < 128) bs[t] = (t < SCAN_BLOCKS) ? ptot[t] : 0;
  __syncthreads();
  for (int off = 1; off < 128; off <<= 1) {
    int u = 0;
    if (t < 128 && t >= off) u = bs[t - off];
    __syncthreads();
    if (t < 128 && t >= off) bs[t] += u;
    __syncthreads();
  }
  const int idx = blockIdx.x * 256 + t;
  if (idx >= N_NODES) return;
  const int bid = idx >> 8;
  const int boff = (bid == 0) ? 0 : bs[bid - 1];
  wptr[idx] = boff + lpre[idx];
  invc[idx] = 1.0f / fmaxf((float)cnt[idx], 1.0f);
  const int bt = batch[idx];
  if (idx == 0)
    for (int g = 0; g <= bt; ++g) grp[g] = 0;
  else {
    const int pb = batch[idx - 1];
    for (int g = pb + 1; g <= bt; ++g) grp[g] = idx;
  }
  if (idx == N_NODES - 1)
    for (int g = bt + 1; g <= NG; ++g) grp[g] = N_NODES;
}

// ---------------- build: CSR scatter + bf16 pack in CSR order (fused) -------
extern "C" __global__ void __launch_bounds__(256)
k_build(const int* __restrict__ ei, int* __restrict__ wptr,
        int* __restrict__ srcs, int* __restrict__ dsts,
        const float* __restrict__ ea, unsigned short* __restrict__ eapb) {
  __shared__ int lpos[256];
  const int e0 = blockIdx.x * 256;
  {
    const int e = e0 + threadIdx.x;
    const int d = ei[N_EDGES + e];
    const int pos = atomicAdd(&wptr[d], 1);
    srcs[pos] = ei[e];
    dsts[pos] = d;
    lpos[threadIdx.x] = pos;
  }
  __syncthreads();
  const int l16 = threadIdx.x & 15;
  const int sub = threadIdx.x >> 4;  // 0..15
#pragma unroll
  for (int r = 0; r < 16; ++r) {
    const int eb = r * 16 + sub;
    const size_t ge = e0 + eb;
    const int pos = lpos[eb];
    unsigned short o0 = 0, o1 = 0, o2 = 0, o3 = 0;
    if (l16 < 12) {
      const float4 v = *(const float4*)(ea + ge * EFEAT + l16 * 4);
      o0 = f2bf(v.x); o1 = f2bf(v.y); o2 = f2bf(v.z); o3 = f2bf(v.w);
    } else if (l16 == 12) {
      const float2 v = *(const float2*)(ea + ge * EFEAT + 48);
      o0 = f2bf(v.x); o1 = f2bf(v.y);
    }
    u16x4 st;
    st[0] = o0; st[1] = o1; st[2] = o2; st[3] = o3;
    *(u16x4*)(eapb + ((size_t)pos << 6) + l16 * 4) = st;
  }
}

// ---------------- node projections -> packed bf16; fused BN update ----------
// Also zeroes aggr_z (the buffer the following k_edgemm accumulates into).
extern "C" __global__ void __launch_bounds__(256)
k_nodeproj(const float* __restrict__ hin, float* __restrict__ hout,
           const float* __restrict__ wfp, const float* __restrict__ wsm,
           unsigned short* __restrict__ projd_pk, unsigned short* __restrict__ projs_pk,
           const float* __restrict__ aggr, float* __restrict__ aggr_z,
           const float* __restrict__ invc,
           const float* __restrict__ musum, const float* __restrict__ sqsum,
           const float* __restrict__ gamma, const float* __restrict__ beta,
           int do_bn) {
  const int lane = threadIdx.x & 63;
  const int w = threadIdx.x >> 6;  // 0..3
  const float* W = (w < 2) ? wfp : wsm;
  const int roff = (w & 1) * 64;  // 0=dst rows, 1=src rows
  float wreg[D1];
#pragma unroll
  for (int k = 0; k < D1; ++k) wreg[k] = W[(size_t)(roff + k) * D1 + lane];
  unsigned short* pk = (w & 1) ? projs_pk : projd_pk;
  const int slot = (w < 2) ? 0 : 4;  // Wf -> lo4, Ws -> hi4
  const int poff = (lane >> 2) * 8 + (lane & 3) + slot;
  float r = 0.0f, sh = 0.0f;
  if (do_bn) {
    const float mu = musum[lane] * (1.0f / N_NODES);
    const float var = sqsum[lane] * (1.0f / N_NODES) - mu * mu;
    r = gamma[lane] * rsqrtf(var + BN_EPS);
    sh = beta[lane] - mu * r;
  }
  __shared__ float hl[4][64];
  for (int i = blockIdx.x; i < N_NODES; i += gridDim.x) {
    float hv = hin[(size_t)i * D1 + lane];
    if (do_bn) {
      const float av = aggr[(size_t)i * D1 + lane] * invc[i];
      hv = fmaxf(hv + fmaf(av, r, sh), 0.0f);
      if (w == 0) hout[(size_t)i * D1 + lane] = hv;
    }
    if (w == 1) aggr_z[(size_t)i * D1 + lane] = 0.0f;  // zero for next edgemm
    hl[w][lane] = hv;
    __builtin_amdgcn_wave_barrier();
    const float4* hr = (const float4*)&hl[w][0];
    float acc = 0.0f;
#pragma unroll
    for (int k4 = 0; k4 < D1 / 4; ++k4) {
      const float4 v = hr[k4];
      acc = fmaf(v.x, wreg[4 * k4 + 0], acc);
      acc = fmaf(v.y, wreg[4 * k4 + 1], acc);
      acc = fmaf(v.z, wreg[4 * k4 + 2], acc);
      acc = fmaf(v.w, wreg[4 * k4 + 3], acc);
    }
    pk[(size_t)i * 128 + poff] = f2bf(acc);
    __builtin_amdgcn_wave_barrier();
  }
}

// ---------------- MFMA edge kernel: 4 waves/block, 1 tile per wave ----------
// XCD-aware swizzle: each XCD owns a contiguous tile range so dst-row gathers
// and idx/eapb streams stay XCD-L2-local. Plain launch_bounds (R9 lesson:
// forcing min-waves spills to scratch).
extern "C" __global__ void __launch_bounds__(256)
k_edgemm(const unsigned short* __restrict__ projd_pk,
         const unsigned short* __restrict__ projs_pk,
         const unsigned short* __restrict__ eapb,
         const int* __restrict__ srcs, const int* __restrict__ dsts,
         const unsigned short* __restrict__ Bp,
         const float* __restrict__ bfp, const float* __restrict__ bsp,
         float* __restrict__ aggr, float* __restrict__ musum,
         float* __restrict__ sqsum) {
  const int lane = threadIdx.x & 63;
  const int wv = threadIdx.x >> 6;
  const int col = lane & 15;
  const int quad = lane >> 4;
  __shared__ float mlds[4][16][68];

  // swizzle: blockIdx -> (xcd, slot) -> contiguous vbid range per XCD
  const int vbid = (blockIdx.x & 7) * 938 + (blockIdx.x >> 3);
  if (blockIdx.x == 0 && wv == 0) {  // zero stats accumulators for k_stats
    musum[lane] = 0.0f;
    sqsum[lane] = 0.0f;
  }
  if (vbid >= EDGE_BLOCKS) return;

  const int t = vbid * 4 + wv;  // tile id; exactly NTILES waves
  const int base = t * 16;

  // independent streamed loads — all in flight together
  const int4 d4 = *(const int4*)(dsts + base + quad * 4);
  const int4 s4 = *(const int4*)(srcs + base + quad * 4);
  const int* dr = (const int*)&d4;
  const int* sr = (const int*)&s4;
  const bf16x8 Af0 = *(const bf16x8*)(eapb + ((size_t)(base + col) << 6) + quad * 8);
  const bf16x8 Af1 = *(const bf16x8*)(eapb + ((size_t)(base + col) << 6) + 32 + quad * 8);

  bf16x8 Bf[2][2][4];
#pragma unroll
  for (int m = 0; m < 2; ++m)
#pragma unroll
    for (int tt = 0; tt < 2; ++tt)
#pragma unroll
      for (int n = 0; n < 4; ++n)
        Bf[m][tt][n] = *(const bf16x8*)(Bp + ((((m * 2 + tt) * 4 + n) * 64 + lane) * 8));

  const f32x4 bf4 = *(const f32x4*)(bfp + col * 4);
  const f32x4 bs4 = *(const f32x4*)(bsp + col * 4);

  // C init from packed bf16 projections: 2 gathered 16B loads per edge row
  f32x4 aF[4], aS[4];
#pragma unroll
  for (int r = 0; r < 4; ++r) {
    const int d = dr[r];
    const int s = sr[r];
    const u16x8 pd = *(const u16x8*)(projd_pk + (size_t)d * 128 + col * 8);
    const u16x8 ss = *(const u16x8*)(projs_pk + (size_t)s * 128 + col * 8);
#pragma unroll
    for (int n = 0; n < 4; ++n) {
      aF[n][r] = bfu(pd[n]) + bfu(ss[n]) + bf4[n];
      aS[n][r] = bfu(pd[n + 4]) + bfu(ss[n + 4]) + bs4[n];
    }
  }

#pragma unroll
  for (int n = 0; n < 4; ++n) {
    aF[n] = __builtin_amdgcn_mfma_f32_16x16x32_bf16(Af0, Bf[0][0][n], aF[n], 0, 0, 0);
    aF[n] = __builtin_amdgcn_mfma_f32_16x16x32_bf16(Af1, Bf[0][1][n], aF[n], 0, 0, 0);
    aS[n] = __builtin_amdgcn_mfma_f32_16x16x32_bf16(Af0, Bf[1][0][n], aS[n], 0, 0, 0);
    aS[n] = __builtin_amdgcn_mfma_f32_16x16x32_bf16(Af1, Bf[1][1][n], aS[n], 0, 0, 0);
  }

  // epilogue: m = sigmoid(af) * softplus(as) -> LDS tile
#pragma unroll
  for (int r = 0; r < 4; ++r) {
    f32x4 mv;
#pragma unroll
    for (int n = 0; n < 4; ++n) {
      const float af = aF[n][r];
      const float as = aS[n][r];
      const float sg = __builtin_amdgcn_rcpf(1.0f + __expf(-af));
      const float sp = fmaxf(as, 0.0f) + __logf(1.0f + __expf(-fabsf(as)));
      mv[n] = sg * sp;
    }
    *(f32x4*)&mlds[wv][quad * 4 + r][col * 4] = mv;
  }
  __builtin_amdgcn_wave_barrier();

  // segmented reduce over the 16 dst-sorted CSR rows (raw sums; mean later)
  float sum = 0.0f;
  int dcur = dsts[base];
#pragma unroll
  for (int p = 0; p < 16; ++p) {
    sum += mlds[wv][p][lane];
    const int dnxt = (p < 15) ? dsts[base + p + 1] : -1;
    if (dnxt != dcur) {
      atomicAdd(&aggr[(size_t)dcur * D1 + lane], sum);
      sum = 0.0f;
      dcur = dnxt;
    }
  }
}

// ---------------- BN stats over aggr*invc ----------------
extern "C" __global__ void __launch_bounds__(256)
k_stats(const float* __restrict__ aggr, const float* __restrict__ invc,
        float* __restrict__ musum, float* __restrict__ sqsum) {
  const int j = threadIdx.x & 63;
  const int rid = (blockIdx.x * blockDim.x + threadIdx.x) >> 6;
  const int rstr = (gridDim.x * blockDim.x) >> 6;
  float s = 0.0f, sq = 0.0f;
  for (int i = rid; i < N_NODES; i += rstr) {
    const float v = aggr[(size_t)i * D1 + j] * invc[i];
    s += v;
    sq = fmaf(v, v, sq);
  }
  __shared__ float ls[256], lq[256];
  ls[threadIdx.x] = s;
  lq[threadIdx.x] = sq;
  __syncthreads();
  if (threadIdx.x < 64) {
    s = ls[j] + ls[64 + j] + ls[128 + j] + ls[192 + j];
    sq = lq[j] + lq[64 + j] + lq[128 + j] + lq[192 + j];
    atomicAdd(&musum[j], s);
    atomicAdd(&sqsum[j], sq);
  }
}

// ---------------- fused pool (final BN update) + MLP chain ------------------
extern "C" __global__ void __launch_bounds__(256)
k_poolmlp(const float* __restrict__ h, const float* __restrict__ aggr,
          const float* __restrict__ invc,
          const float* __restrict__ musum, const float* __restrict__ sqsum,
          const float* __restrict__ gamma, const float* __restrict__ beta,
          const int* __restrict__ grp,
          const float* __restrict__ lin1_w, const float* __restrict__ lin1_b,
          const float* __restrict__ fc_w, const float* __restrict__ fc_b,
          const float* __restrict__ lin2_w, const float* __restrict__ lin2_b,
          float* __restrict__ out) {
  const int g = blockIdx.x;
  const int lane = threadIdx.x & 63;
  const int wv = threadIdx.x >> 6;
  const float mu = musum[lane] * (1.0f / N_NODES);
  const float var = sqsum[lane] * (1.0f / N_NODES) - mu * mu;
  const float r = gamma[lane] * rsqrtf(var + BN_EPS);
  const float sh = beta[lane] - mu * r;
  const int s = grp[g], e = grp[g + 1];
  float acc = 0.0f;
  for (int i = s + wv; i < e; i += 4) {
    const float hv = h[(size_t)i * D1 + lane];
    const float av = aggr[(size_t)i * D1 + lane] * invc[i];
    acc += fmaxf(hv + fmaf(av, r, sh), 0.0f);
  }
  __shared__ float red[4][64];
  __shared__ float vin[64];
  red[wv][lane] = acc;
  __syncthreads();
  const int j = threadIdx.x;
  float v = 0.0f;
  if (j < 64) {
    const float inv = 1.0f / fmaxf((float)(e - s), 1.0f);
    v = (red[0][j] + red[1][j] + red[2][j] + red[3][j]) * inv;
  }
  for (int layer = 0; layer < 3; ++layer) {
    if (j < 64) vin[j] = v;
    __syncthreads();
    if (j < 64) {
      const float* W;
      const float* B;
      if (layer == 0) {
        W = lin1_w;
        B = lin1_b;
      } else {
        W = fc_w + (size_t)(layer - 1) * D1 * D1;
        B = fc_b + (size_t)(layer - 1) * D1;
      }
      float a2 = B[j];
#pragma unroll 16
      for (int k = 0; k < D1; ++k) a2 = fmaf(vin[k], W[k * D1 + j], a2);
      v = fmaxf(a2, 0.0f);
    }
    __syncthreads();
  }
  if (j < 64) {
    float p = v * lin2_w[j];
#pragma unroll
    for (int off = 32; off > 0; off >>= 1) p += __shfl_down(p, off);
    if (j == 0) out[g] = p + lin2_b[0];
  }
}

extern "C" void kernel_launch(void* const* d_in, const int* in_sizes, int n_in,
                              void* d_out, int out_size, void* d_ws, size_t ws_size,
                              hipStream_t stream) {
  const float* x        = (const float*)d_in[0];
  const float* ea       = (const float*)d_in[1];
  const float* lin0_w   = (const float*)d_in[2];
  const float* lin0_b   = (const float*)d_in[3];
  const float* conv_wf  = (const float*)d_in[4];
  const float* conv_bf  = (const float*)d_in[5];
  const float* conv_ws  = (const float*)d_in[6];
  const float* conv_bs  = (const float*)d_in[7];
  const float* bn_gamma = (const float*)d_in[8];
  const float* bn_beta  = (const float*)d_in[9];
  const float* lin1_w   = (const float*)d_in[10];
  const float* lin1_b   = (const float*)d_in[11];
  const float* fc_w     = (const float*)d_in[12];
  const float* fc_b     = (const float*)d_in[13];
  const float* lin2_w   = (const float*)d_in[14];
  const float* lin2_b   = (const float*)d_in[15];
  const int*   ei       = (const int*)d_in[16];
  const int*   batch    = (const int*)d_in[17];

  uintptr_t p = (uintptr_t)d_ws;
  auto alloc = [&](size_t bytes) {
    p = (p + 255) & ~(size_t)255;
    void* r = (void*)p;
    p += bytes;
    return r;
  };
  float* h0     = (float*)alloc((size_t)N_NODES * 64 * 4);
  float* h1     = (float*)alloc((size_t)N_NODES * 64 * 4);
  unsigned short* projd_pk = (unsigned short*)alloc((size_t)N_NODES * 128 * 2);
  unsigned short* projs_pk = (unsigned short*)alloc((size_t)N_NODES * 128 * 2);
  float* aggrA  = (float*)alloc((size_t)N_NODES * 64 * 4);
  float* aggrB  = (float*)alloc((size_t)N_NODES * 64 * 4);
  float* musum  = (float*)alloc(128 * 4);
  float* sqsum  = musum + 64;
  float* invc   = (float*)alloc((size_t)N_NODES * 4);
  int*   cnt    = (int*)alloc((size_t)N_NODES * 4);
  int*   lpre   = (int*)alloc((size_t)N_NODES * 4);
  int*   ptot   = (int*)alloc((size_t)SCAN_BLOCKS * 4);
  int*   wptr   = (int*)alloc((size_t)N_NODES * 4);
  int*   srcs   = (int*)alloc((size_t)N_EDGES * 4);
  int*   dsts   = (int*)alloc((size_t)N_EDGES * 4);
  int*   grp    = (int*)alloc((size_t)(NG + 1) * 4);
  unsigned short* eapb = (unsigned short*)alloc((size_t)N_EDGES * 64 * 2);
  unsigned short* Bp   = (unsigned short*)alloc((size_t)NL * 16 * 64 * 8 * 2);

  hipMemsetAsync(cnt, 0, N_NODES * sizeof(int), stream);
  k_init<<<LIN0_BLOCKS + CNT_BLOCKS + WPREP_BLOCKS, 256, 0, stream>>>(
      x, lin0_w, lin0_b, h0, ei, cnt, conv_wf, conv_ws, Bp);
  k_scan1<<<SCAN_BLOCKS, 256, 0, stream>>>(cnt, lpre, ptot);
  k_scan23<<<SCAN_BLOCKS, 256, 0, stream>>>(cnt, lpre, ptot, batch, wptr, invc, grp);
  k_build<<<N_EDGES / 256, 256, 0, stream>>>(ei, wptr, srcs, dsts, ea, eapb);

  float* aggr_of[NL] = {aggrA, aggrB, aggrA};
  const float* hin_of[NL]  = {h0, h0, h1};
  float* hout_of[NL]       = {h0, h1, h0};

  for (int l = 0; l < NL; ++l) {
    const float* wfl = conv_wf + (size_t)l * ZD * D1;
    const float* wsl = conv_ws + (size_t)l * ZD * D1;
    k_nodeproj<<<1024, 256, 0, stream>>>(
        hin_of[l], hout_of[l], wfl, wsl, projd_pk, projs_pk,
        (l == 0) ? nullptr : aggr_of[l - 1], aggr_of[l], invc, musum, sqsum,
        bn_gamma + (size_t)(l - 1) * D1, bn_beta + (size_t)(l - 1) * D1, l != 0);
    k_edgemm<<<EDGE_GRID, 256, 0, stream>>>(
        projd_pk, projs_pk, eapb, srcs, dsts,
        Bp + (size_t)l * 16 * 64 * 8,
        conv_bf + (size_t)l * D1, conv_bs + (size_t)l * D1,
        aggr_of[l], musum, sqsum);
    k_stats<<<256, 256, 0, stream>>>(aggr_of[l], invc, musum, sqsum);
  }

  k_poolmlp<<<NG, 256, 0, stream>>>(h0, aggr_of[2], invc, musum, sqsum,
                                    bn_gamma + (size_t)2 * D1, bn_beta + (size_t)2 * D1,
                                    grp, lin1_w, lin1_b, fc_w, fc_b,
                                    lin2_w, lin2_b, (float*)d_out);
}

// Round 13
// 619.627 us; speedup vs baseline: 2.7734x; 1.0072x over previous
//
#include <hip/hip_runtime.h>
#include <hip/hip_bf16.h>

#define N_NODES 30000
#define N_EDGES 480000
#define NFEAT 92
#define EFEAT 50
#define D1 64
#define ZD 178
#define NL 3
#define NG 256
#define BN_EPS 1e-5f
#define NTILES (N_EDGES / 16)     // 30000 tiles, 1 per wave
#define EDGE_BLOCKS 7500          // logical blocks (4 waves each)
#define EDGE_GRID 7504            // 8 XCDs x 938, guard vbid < 7500

#define LIN0_BLOCKS 512
#define CNT_BLOCKS 1875    // E / 256
#define WPREP_BLOCKS 96    // NL*16*64*8 / 256
#define SCAN_BLOCKS ((N_NODES + 255) / 256)  // 118
#define BUILD_BLOCKS 1875  // E / 256
#define NP_BLOCKS 1024     // nodeproj blocks fused into k_build

typedef __attribute__((ext_vector_type(8))) short bf16x8;
typedef __attribute__((ext_vector_type(8))) unsigned short u16x8;
typedef __attribute__((ext_vector_type(4))) unsigned short u16x4;
typedef __attribute__((ext_vector_type(4))) float f32x4;

static __device__ __forceinline__ unsigned short f2bf(float v) {
  __hip_bfloat16 b = __float2bfloat16(v);
  return *(unsigned short*)&b;
}
static __device__ __forceinline__ float bfu(unsigned short u) {
  union { unsigned int i; float f; } c;
  c.i = ((unsigned int)u) << 16;
  return c.f;
}

// ---------------- shared nodeproj body (used by k_build fused path and k_nodeproj)
static __device__ __forceinline__ void nodeproj_body(
    int blk0, int nblk, const float* __restrict__ hin, float* __restrict__ hout,
    const float* __restrict__ wfp, const float* __restrict__ wsm,
    unsigned short* __restrict__ projd_pk, unsigned short* __restrict__ projs_pk,
    const float* __restrict__ aggr, float* __restrict__ aggr_z,
    const float* __restrict__ invc, const float* __restrict__ musum,
    const float* __restrict__ sqsum, const float* __restrict__ gamma,
    const float* __restrict__ beta, int do_bn, float (*hl)[64]) {
  const int lane = threadIdx.x & 63;
  const int w = threadIdx.x >> 6;  // 0..3
  const float* W = (w < 2) ? wfp : wsm;
  const int roff = (w & 1) * 64;  // 0=dst rows, 1=src rows
  float wreg[D1];
#pragma unroll
  for (int k = 0; k < D1; ++k) wreg[k] = W[(size_t)(roff + k) * D1 + lane];
  unsigned short* pk = (w & 1) ? projs_pk : projd_pk;
  const int slot = (w < 2) ? 0 : 4;  // Wf -> lo4, Ws -> hi4
  const int poff = (lane >> 2) * 8 + (lane & 3) + slot;
  float r = 0.0f, sh = 0.0f;
  if (do_bn) {
    const float mu = musum[lane] * (1.0f / N_NODES);
    const float var = sqsum[lane] * (1.0f / N_NODES) - mu * mu;
    r = gamma[lane] * rsqrtf(var + BN_EPS);
    sh = beta[lane] - mu * r;
  }
  for (int i = blk0; i < N_NODES; i += nblk) {
    float hv = hin[(size_t)i * D1 + lane];
    if (do_bn) {
      const float av = aggr[(size_t)i * D1 + lane] * invc[i];
      hv = fmaxf(hv + fmaf(av, r, sh), 0.0f);
      if (w == 0) hout[(size_t)i * D1 + lane] = hv;
    }
    if (w == 1) aggr_z[(size_t)i * D1 + lane] = 0.0f;  // zero for next edgemm
    hl[w][lane] = hv;
    __builtin_amdgcn_wave_barrier();
    const float4* hr = (const float4*)&hl[w][0];
    float acc = 0.0f;
#pragma unroll
    for (int k4 = 0; k4 < D1 / 4; ++k4) {
      const float4 v = hr[k4];
      acc = fmaf(v.x, wreg[4 * k4 + 0], acc);
      acc = fmaf(v.y, wreg[4 * k4 + 1], acc);
      acc = fmaf(v.z, wreg[4 * k4 + 2], acc);
      acc = fmaf(v.w, wreg[4 * k4 + 3], acc);
    }
    pk[(size_t)i * 128 + poff] = f2bf(acc);
    __builtin_amdgcn_wave_barrier();
  }
}

// ---------------- init: lin0 + dst counts + B fragments (block-range split) --
extern "C" __global__ void __launch_bounds__(256)
k_init(const float* __restrict__ x, const float* __restrict__ w,
       const float* __restrict__ b, float* __restrict__ h,
       const int* __restrict__ ei, int* __restrict__ cnt,
       const float* __restrict__ conv_wf, const float* __restrict__ conv_ws,
       unsigned short* __restrict__ Bp) {
  const int blk = blockIdx.x;
  if (blk < LIN0_BLOCKS) {
    const int lane = threadIdx.x & 63;
    const int wave = (blk * 256 + threadIdx.x) >> 6;
    const int nw = (LIN0_BLOCKS * 256) >> 6;
    float wreg[NFEAT];
#pragma unroll
    for (int k = 0; k < NFEAT; ++k) wreg[k] = w[k * D1 + lane];
    const float bj = b[lane];
    for (int i = wave; i < N_NODES; i += nw) {
      const float2* xr = (const float2*)(x + (size_t)i * NFEAT);
      float acc = bj;
#pragma unroll
      for (int k = 0; k < NFEAT / 2; ++k) {
        const float2 v = xr[k];
        acc = fmaf(v.x, wreg[2 * k], acc);
        acc = fmaf(v.y, wreg[2 * k + 1], acc);
      }
      h[(size_t)i * D1 + lane] = fmaxf(acc, 0.0f);
    }
  } else if (blk < LIN0_BLOCKS + CNT_BLOCKS) {
    const int e = (blk - LIN0_BLOCKS) * 256 + threadIdx.x;
    if (e < N_EDGES) atomicAdd(&cnt[ei[N_EDGES + e]], 1);
  } else {
    const int idx = (blk - LIN0_BLOCKS - CNT_BLOCKS) * 256 + threadIdx.x;
    const int j = idx & 7;
    const int lane = (idx >> 3) & 63;
    const int frag = (idx >> 9) & 15;  // (m*2+t)*4+n
    const int l = idx >> 13;
    const int n = frag & 3;
    const int t = (frag >> 2) & 1;
    const int m = frag >> 3;
    const int k = t * 32 + (lane >> 4) * 8 + j;
    const int feat = (lane & 15) * 4 + n;
    float v = 0.0f;
    if (k < EFEAT) {
      const float* W = (m == 0) ? conv_wf : conv_ws;
      v = W[(size_t)l * ZD * D1 + (size_t)(128 + k) * D1 + feat];
    }
    Bp[idx] = f2bf(v);
  }
}

// ---------------- scan phase 1: per-block partial sums ----------------
extern "C" __global__ void __launch_bounds__(256)
k_scan1(const int* __restrict__ cnt, int* __restrict__ lpre, int* __restrict__ ptot) {
  const int t = threadIdx.x;
  const int idx = blockIdx.x * 256 + t;
  const int v = (idx < N_NODES) ? cnt[idx] : 0;
  __shared__ int bs[256];
  bs[t] = v;
  __syncthreads();
  for (int off = 1; off < 256; off <<= 1) {
    int u = (t >= off) ? bs[t - off] : 0;
    __syncthreads();
    bs[t] += u;
    __syncthreads();
  }
  if (idx < N_NODES) lpre[idx] = bs[t] - v;
  if (t == 255) ptot[blockIdx.x] = bs[255];
}

// scan phase 2+3: redundant block-offset scan + wptr/invc/grp
extern "C" __global__ void __launch_bounds__(256)
k_scan23(const int* __restrict__ cnt, const int* __restrict__ lpre,
         const int* __restrict__ ptot, const int* __restrict__ batch,
         int* __restrict__ wptr, float* __restrict__ invc,
         int* __restrict__ grp) {
  __shared__ int bs[128];
  const int t = threadIdx.x;
  if (t < 128) bs[t] = (t < SCAN_BLOCKS) ? ptot[t] : 0;
  __syncthreads();
  for (int off = 1; off < 128; off <<= 1) {
    int u = 0;
    if (t < 128 && t >= off) u = bs[t - off];
    __syncthreads();
    if (t < 128 && t >= off) bs[t] += u;
    __syncthreads();
  }
  const int idx = blockIdx.x * 256 + t;
  if (idx >= N_NODES) return;
  const int bid = idx >> 8;
  const int boff = (bid == 0) ? 0 : bs[bid - 1];
  wptr[idx] = boff + lpre[idx];
  invc[idx] = 1.0f / fmaxf((float)cnt[idx], 1.0f);
  const int bt = batch[idx];
  if (idx == 0)
    for (int g = 0; g <= bt; ++g) grp[g] = 0;
  else {
    const int pb = batch[idx - 1];
    for (int g = pb + 1; g <= bt; ++g) grp[g] = idx;
  }
  if (idx == N_NODES - 1)
    for (int g = bt + 1; g <= NG; ++g) grp[g] = N_NODES;
}

// ---------------- build: CSR scatter (int2 dst,src) + bf16 pack + nodeproj0 --
// blocks [0, BUILD_BLOCKS): scatter+pack; [BUILD_BLOCKS, +NP_BLOCKS): nodeproj l=0.
extern "C" __global__ void __launch_bounds__(256)
k_build(const int* __restrict__ ei, int* __restrict__ wptr,
        int2* __restrict__ ds2, const float* __restrict__ ea,
        unsigned short* __restrict__ eapb,
        const float* __restrict__ h0, const float* __restrict__ wfl,
        const float* __restrict__ wsl, unsigned short* __restrict__ projd_pk,
        unsigned short* __restrict__ projs_pk, float* __restrict__ aggrA) {
  __shared__ __align__(16) int lpos[256];
  if (blockIdx.x >= BUILD_BLOCKS) {
    nodeproj_body(blockIdx.x - BUILD_BLOCKS, NP_BLOCKS, h0, nullptr, wfl, wsl,
                  projd_pk, projs_pk, nullptr, aggrA, nullptr, nullptr, nullptr,
                  nullptr, nullptr, 0, (float(*)[64])lpos);
    return;
  }
  const int e0 = blockIdx.x * 256;
  {
    const int e = e0 + threadIdx.x;
    const int d = ei[N_EDGES + e];
    const int pos = atomicAdd(&wptr[d], 1);
    ds2[pos] = make_int2(d, ei[e]);  // one 8B scatter (half the sectors)
    lpos[threadIdx.x] = pos;
  }
  __syncthreads();
  const int l16 = threadIdx.x & 15;
  const int sub = threadIdx.x >> 4;  // 0..15
#pragma unroll
  for (int r = 0; r < 16; ++r) {
    const int eb = r * 16 + sub;
    const size_t ge = e0 + eb;
    const int pos = lpos[eb];
    unsigned short o0 = 0, o1 = 0, o2 = 0, o3 = 0;
    if (l16 < 12) {
      const float4 v = *(const float4*)(ea + ge * EFEAT + l16 * 4);
      o0 = f2bf(v.x); o1 = f2bf(v.y); o2 = f2bf(v.z); o3 = f2bf(v.w);
    } else if (l16 == 12) {
      const float2 v = *(const float2*)(ea + ge * EFEAT + 48);
      o0 = f2bf(v.x); o1 = f2bf(v.y);
    }
    u16x4 st;
    st[0] = o0; st[1] = o1; st[2] = o2; st[3] = o3;
    *(u16x4*)(eapb + ((size_t)pos << 6) + l16 * 4) = st;
  }
}

// ---------------- standalone node projections (layers 1,2) ----------------
extern "C" __global__ void __launch_bounds__(256)
k_nodeproj(const float* __restrict__ hin, float* __restrict__ hout,
           const float* __restrict__ wfp, const float* __restrict__ wsm,
           unsigned short* __restrict__ projd_pk, unsigned short* __restrict__ projs_pk,
           const float* __restrict__ aggr, float* __restrict__ aggr_z,
           const float* __restrict__ invc,
           const float* __restrict__ musum, const float* __restrict__ sqsum,
           const float* __restrict__ gamma, const float* __restrict__ beta) {
  __shared__ float hl[4][64];
  nodeproj_body(blockIdx.x, gridDim.x, hin, hout, wfp, wsm, projd_pk, projs_pk,
                aggr, aggr_z, invc, musum, sqsum, gamma, beta, 1, hl);
}

// ---------------- MFMA edge kernel: 4 waves/block, 1 tile per wave ----------
// XCD-aware swizzle; (dst,src) packed int2. Plain launch_bounds (R9 lesson).
extern "C" __global__ void __launch_bounds__(256)
k_edgemm(const unsigned short* __restrict__ projd_pk,
         const unsigned short* __restrict__ projs_pk,
         const unsigned short* __restrict__ eapb,
         const int2* __restrict__ ds2,
         const unsigned short* __restrict__ Bp,
         const float* __restrict__ bfp, const float* __restrict__ bsp,
         float* __restrict__ aggr, float* __restrict__ musum,
         float* __restrict__ sqsum) {
  const int lane = threadIdx.x & 63;
  const int wv = threadIdx.x >> 6;
  const int col = lane & 15;
  const int quad = lane >> 4;
  __shared__ float mlds[4][16][68];

  const int vbid = (blockIdx.x & 7) * 938 + (blockIdx.x >> 3);
  if (blockIdx.x == 0 && wv == 0) {  // zero stats accumulators for k_stats
    musum[lane] = 0.0f;
    sqsum[lane] = 0.0f;
  }
  if (vbid >= EDGE_BLOCKS) return;

  const int t = vbid * 4 + wv;  // tile id; exactly NTILES waves
  const int base = t * 16;

  // independent streamed loads — all in flight together
  const int4 p01 = *(const int4*)(ds2 + base + quad * 4);      // edges r=0,1
  const int4 p23 = *(const int4*)(ds2 + base + quad * 4 + 2);  // edges r=2,3
  const int dr[4] = {p01.x, p01.z, p23.x, p23.z};
  const int sr[4] = {p01.y, p01.w, p23.y, p23.w};
  const bf16x8 Af0 = *(const bf16x8*)(eapb + ((size_t)(base + col) << 6) + quad * 8);
  const bf16x8 Af1 = *(const bf16x8*)(eapb + ((size_t)(base + col) << 6) + 32 + quad * 8);

  bf16x8 Bf[2][2][4];
#pragma unroll
  for (int m = 0; m < 2; ++m)
#pragma unroll
    for (int tt = 0; tt < 2; ++tt)
#pragma unroll
      for (int n = 0; n < 4; ++n)
        Bf[m][tt][n] = *(const bf16x8*)(Bp + ((((m * 2 + tt) * 4 + n) * 64 + lane) * 8));

  const f32x4 bf4 = *(const f32x4*)(bfp + col * 4);
  const f32x4 bs4 = *(const f32x4*)(bsp + col * 4);

  // C init from packed bf16 projections: 2 gathered 16B loads per edge row
  f32x4 aF[4], aS[4];
#pragma unroll
  for (int r = 0; r < 4; ++r) {
    const int d = dr[r];
    const int s = sr[r];
    const u16x8 pd = *(const u16x8*)(projd_pk + (size_t)d * 128 + col * 8);
    const u16x8 ss = *(const u16x8*)(projs_pk + (size_t)s * 128 + col * 8);
#pragma unroll
    for (int n = 0; n < 4; ++n) {
      aF[n][r] = bfu(pd[n]) + bfu(ss[n]) + bf4[n];
      aS[n][r] = bfu(pd[n + 4]) + bfu(ss[n + 4]) + bs4[n];
    }
  }

#pragma unroll
  for (int n = 0; n < 4; ++n) {
    aF[n] = __builtin_amdgcn_mfma_f32_16x16x32_bf16(Af0, Bf[0][0][n], aF[n], 0, 0, 0);
    aF[n] = __builtin_amdgcn_mfma_f32_16x16x32_bf16(Af1, Bf[0][1][n], aF[n], 0, 0, 0);
    aS[n] = __builtin_amdgcn_mfma_f32_16x16x32_bf16(Af0, Bf[1][0][n], aS[n], 0, 0, 0);
    aS[n] = __builtin_amdgcn_mfma_f32_16x16x32_bf16(Af1, Bf[1][1][n], aS[n], 0, 0, 0);
  }

  // epilogue: m = sigmoid(af) * softplus(as) -> LDS tile
#pragma unroll
  for (int r = 0; r < 4; ++r) {
    f32x4 mv;
#pragma unroll
    for (int n = 0; n < 4; ++n) {
      const float af = aF[n][r];
      const float as = aS[n][r];
      const float sg = __builtin_amdgcn_rcpf(1.0f + __expf(-af));
      const float sp = fmaxf(as, 0.0f) + __logf(1.0f + __expf(-fabsf(as)));
      mv[n] = sg * sp;
    }
    *(f32x4*)&mlds[wv][quad * 4 + r][col * 4] = mv;
  }
  __builtin_amdgcn_wave_barrier();

  // segmented reduce over the 16 dst-sorted CSR rows (raw sums; mean later)
  float sum = 0.0f;
  int dcur = ds2[base].x;
#pragma unroll
  for (int p = 0; p < 16; ++p) {
    sum += mlds[wv][p][lane];
    const int dnxt = (p < 15) ? ds2[base + p + 1].x : -1;
    if (dnxt != dcur) {
      atomicAdd(&aggr[(size_t)dcur * D1 + lane], sum);
      sum = 0.0f;
      dcur = dnxt;
    }
  }
}

// ---------------- BN stats over aggr*invc ----------------
extern "C" __global__ void __launch_bounds__(256)
k_stats(const float* __restrict__ aggr, const float* __restrict__ invc,
        float* __restrict__ musum, float* __restrict__ sqsum) {
  const int j = threadIdx.x & 63;
  const int rid = (blockIdx.x * blockDim.x + threadIdx.x) >> 6;
  const int rstr = (gridDim.x * blockDim.x) >> 6;
  float s = 0.0f, sq = 0.0f;
  for (int i = rid; i < N_NODES; i += rstr) {
    const float v = aggr[(size_t)i * D1 + j] * invc[i];
    s += v;
    sq = fmaf(v, v, sq);
  }
  __shared__ float ls[256], lq[256];
  ls[threadIdx.x] = s;
  lq[threadIdx.x] = sq;
  __syncthreads();
  if (threadIdx.x < 64) {
    s = ls[j] + ls[64 + j] + ls[128 + j] + ls[192 + j];
    sq = lq[j] + lq[64 + j] + lq[128 + j] + lq[192 + j];
    atomicAdd(&musum[j], s);
    atomicAdd(&sqsum[j], sq);
  }
}

// ---------------- fused pool (final BN update) + MLP chain ------------------
extern "C" __global__ void __launch_bounds__(256)
k_poolmlp(const float* __restrict__ h, const float* __restrict__ aggr,
          const float* __restrict__ invc,
          const float* __restrict__ musum, const float* __restrict__ sqsum,
          const float* __restrict__ gamma, const float* __restrict__ beta,
          const int* __restrict__ grp,
          const float* __restrict__ lin1_w, const float* __restrict__ lin1_b,
          const float* __restrict__ fc_w, const float* __restrict__ fc_b,
          const float* __restrict__ lin2_w, const float* __restrict__ lin2_b,
          float* __restrict__ out) {
  const int g = blockIdx.x;
  const int lane = threadIdx.x & 63;
  const int wv = threadIdx.x >> 6;
  const float mu = musum[lane] * (1.0f / N_NODES);
  const float var = sqsum[lane] * (1.0f / N_NODES) - mu * mu;
  const float r = gamma[lane] * rsqrtf(var + BN_EPS);
  const float sh = beta[lane] - mu * r;
  const int s = grp[g], e = grp[g + 1];
  float acc = 0.0f;
  for (int i = s + wv; i < e; i += 4) {
    const float hv = h[(size_t)i * D1 + lane];
    const float av = aggr[(size_t)i * D1 + lane] * invc[i];
    acc += fmaxf(hv + fmaf(av, r, sh), 0.0f);
  }
  __shared__ float red[4][64];
  __shared__ float vin[64];
  red[wv][lane] = acc;
  __syncthreads();
  const int j = threadIdx.x;
  float v = 0.0f;
  if (j < 64) {
    const float inv = 1.0f / fmaxf((float)(e - s), 1.0f);
    v = (red[0][j] + red[1][j] + red[2][j] + red[3][j]) * inv;
  }
  for (int layer = 0; layer < 3; ++layer) {
    if (j < 64) vin[j] = v;
    __syncthreads();
    if (j < 64) {
      const float* W;
      const float* B;
      if (layer == 0) {
        W = lin1_w;
        B = lin1_b;
      } else {
        W = fc_w + (size_t)(layer - 1) * D1 * D1;
        B = fc_b + (size_t)(layer - 1) * D1;
      }
      float a2 = B[j];
#pragma unroll 16
      for (int k = 0; k < D1; ++k) a2 = fmaf(vin[k], W[k * D1 + j], a2);
      v = fmaxf(a2, 0.0f);
    }
    __syncthreads();
  }
  if (j < 64) {
    float p = v * lin2_w[j];
#pragma unroll
    for (int off = 32; off > 0; off >>= 1) p += __shfl_down(p, off);
    if (j == 0) out[g] = p + lin2_b[0];
  }
}

extern "C" void kernel_launch(void* const* d_in, const int* in_sizes, int n_in,
                              void* d_out, int out_size, void* d_ws, size_t ws_size,
                              hipStream_t stream) {
  const float* x        = (const float*)d_in[0];
  const float* ea       = (const float*)d_in[1];
  const float* lin0_w   = (const float*)d_in[2];
  const float* lin0_b   = (const float*)d_in[3];
  const float* conv_wf  = (const float*)d_in[4];
  const float* conv_bf  = (const float*)d_in[5];
  const float* conv_ws  = (const float*)d_in[6];
  const float* conv_bs  = (const float*)d_in[7];
  const float* bn_gamma = (const float*)d_in[8];
  const float* bn_beta  = (const float*)d_in[9];
  const float* lin1_w   = (const float*)d_in[10];
  const float* lin1_b   = (const float*)d_in[11];
  const float* fc_w     = (const float*)d_in[12];
  const float* fc_b     = (const float*)d_in[13];
  const float* lin2_w   = (const float*)d_in[14];
  const float* lin2_b   = (const float*)d_in[15];
  const int*   ei       = (const int*)d_in[16];
  const int*   batch    = (const int*)d_in[17];

  uintptr_t p = (uintptr_t)d_ws;
  auto alloc = [&](size_t bytes) {
    p = (p + 255) & ~(size_t)255;
    void* r = (void*)p;
    p += bytes;
    return r;
  };
  float* h0     = (float*)alloc((size_t)N_NODES * 64 * 4);
  float* h1     = (float*)alloc((size_t)N_NODES * 64 * 4);
  unsigned short* projd_pk = (unsigned short*)alloc((size_t)N_NODES * 128 * 2);
  unsigned short* projs_pk = (unsigned short*)alloc((size_t)N_NODES * 128 * 2);
  float* aggrA  = (float*)alloc((size_t)N_NODES * 64 * 4);
  float* aggrB  = (float*)alloc((size_t)N_NODES * 64 * 4);
  float* musum  = (float*)alloc(128 * 4);
  float* sqsum  = musum + 64;
  float* invc   = (float*)alloc((size_t)N_NODES * 4);
  int*   cnt    = (int*)alloc((size_t)N_NODES * 4);
  int*   lpre   = (int*)alloc((size_t)N_NODES * 4);
  int*   ptot   = (int*)alloc((size_t)SCAN_BLOCKS * 4);
  int*   wptr   = (int*)alloc((size_t)N_NODES * 4);
  int2*  ds2    = (int2*)alloc((size_t)N_EDGES * 8);
  int*   grp    = (int*)alloc((size_t)(NG + 1) * 4);
  unsigned short* eapb = (unsigned short*)alloc((size_t)N_EDGES * 64 * 2);
  unsigned short* Bp   = (unsigned short*)alloc((size_t)NL * 16 * 64 * 8 * 2);

  hipMemsetAsync(cnt, 0, N_NODES * sizeof(int), stream);
  k_init<<<LIN0_BLOCKS + CNT_BLOCKS + WPREP_BLOCKS, 256, 0, stream>>>(
      x, lin0_w, lin0_b, h0, ei, cnt, conv_wf, conv_ws, Bp);
  k_scan1<<<SCAN_BLOCKS, 256, 0, stream>>>(cnt, lpre, ptot);
  k_scan23<<<SCAN_BLOCKS, 256, 0, stream>>>(cnt, lpre, ptot, batch, wptr, invc, grp);
  // fused: CSR build + bf16 pack + nodeproj(l=0)
  k_build<<<BUILD_BLOCKS + NP_BLOCKS, 256, 0, stream>>>(
      ei, wptr, ds2, ea, eapb, h0, conv_wf, conv_ws, projd_pk, projs_pk, aggrA);

  float* aggr_of[NL] = {aggrA, aggrB, aggrA};
  const float* hin_of[NL]  = {h0, h0, h1};
  float* hout_of[NL]       = {h0, h1, h0};

  for (int l = 0; l < NL; ++l) {
    const float* wfl = conv_wf + (size_t)l * ZD * D1;
    const float* wsl = conv_ws + (size_t)l * ZD * D1;
    if (l > 0)
      k_nodeproj<<<1024, 256, 0, stream>>>(
          hin_of[l], hout_of[l], wfl, wsl, projd_pk, projs_pk,
          aggr_of[l - 1], aggr_of[l], invc, musum, sqsum,
          bn_gamma + (size_t)(l - 1) * D1, bn_beta + (size_t)(l - 1) * D1);
    k_edgemm<<<EDGE_GRID, 256, 0, stream>>>(
        projd_pk, projs_pk, eapb, ds2,
        Bp + (size_t)l * 16 * 64 * 8,
        conv_bf + (size_t)l * D1, conv_bs + (size_t)l * D1,
        aggr_of[l], musum, sqsum);
    k_stats<<<256, 256, 0, stream>>>(aggr_of[l], invc, musum, sqsum);
  }

  k_poolmlp<<<NG, 256, 0, stream>>>(h0, aggr_of[2], invc, musum, sqsum,
                                    bn_gamma + (size_t)2 * D1, bn_beta + (size_t)2 * D1,
                                    grp, lin1_w, lin1_b, fc_w, fc_b,
                                    lin2_w, lin2_b, (float*)d_out);
}